// Round 4
// baseline (184.559 us; speedup 1.0000x reference)
//
#include <hip/hip_runtime.h>

// AWGN index channel: rx = idx XOR bitflip-mask(u < BER), codebook gather,
// concat [fine | coarse] per batch row. Exact integer semantics -> absmax 0.
//
// R4: single fused kernel, block-level phase decoupling. Each of 2048 blocks
// owns 160 contiguous symbols (NTOT/2048). Phase 1: threads 0-159 compute
// rx + out-offset for one symbol each into LDS (fully parallel bit-flip,
// ~6 KB of u-reads per block). ONE __syncthreads. Phase 2: 20 iterations of
// LDS-broadcast row -> 512 B L2 codebook gather -> 4 KB contiguous store.
// vs R3: saves a kernel launch, the rx HBM round-trip, and the per-iteration
// rx L2-load dependency in the store stream. vs R1: barrier per 80 KB (not
// 4 KB) and 160 (not 8) threads doing the flip loads.

constexpr int   BITS       = 9;
constexpr float BER        = 0.02f;
constexpr int   Bn         = 64;
constexpr int   HC = 32, WC = 32, HF = 64, WF = 64, D = 128;
constexpr int   NF         = Bn * HF * WF;     // 262144 fine symbols
constexpr int   NC         = Bn * HC * WC;     // 65536 coarse symbols
constexpr int   NTOT       = NF + NC;          // 327680
constexpr int   FINE_ROW   = HF * WF * D;      // 524288 floats
constexpr int   COARSE_ROW = HC * WC * D;      // 131072 floats
constexpr int   ROW        = FINE_ROW + COARSE_ROW; // 655360 floats / batch row

constexpr int   GRID       = 2048;             // 8 blocks/CU
constexpr int   SPB        = NTOT / GRID;      // 160 symbols per block, exact
constexpr int   P2_ITERS   = SPB / 8;          // 20 (8 symbols per block-iter)

__global__ __launch_bounds__(256) void fused_chan_gather(
    const int*   __restrict__ idx_c,
    const int*   __restrict__ idx_f,
    const float* __restrict__ cb_c,
    const float* __restrict__ cb_f,
    const float* __restrict__ u_c,
    const float* __restrict__ u_f,
    float*       __restrict__ out)
{
    __shared__ int s_row[SPB];   // received codebook row (post-flip)
    __shared__ int s_off[SPB];   // output offset in floats (max 41.9M < 2^31)
    __shared__ int s_crs[SPB];   // 1 = coarse codebook

    const int t    = threadIdx.x;
    const int base = blockIdx.x * SPB;

    // ---- Phase 1: bit-flip channel for this block's 160 symbols ----
    if (t < SPB) {
        const int i = base + t;
        const float* u;  const int* idxp;  int local, off, crs;
        if (i < NF) {                       // only block 1638 straddles
            local = i;
            const int b = i >> 12, rem = i & 4095;      // / , % (HF*WF)
            off = b * ROW + rem * D;
            u = u_f;  idxp = idx_f;  crs = 0;
        } else {
            local = i - NF;
            const int b = local >> 10, rem = local & 1023; // / , % (HC*WC)
            off = b * ROW + FINE_ROW + rem * D;
            u = u_c;  idxp = idx_c;  crs = 1;
        }
        const float* up = u + (size_t)local * BITS;
        int flip = 0;
        #pragma unroll
        for (int k = 0; k < BITS; ++k)
            flip |= (up[k] < BER) ? (1 << k) : 0;
        s_row[t] = (idxp[local] ^ flip) & 511;          // clip is a no-op
        s_off[t] = off;
        s_crs[t] = crs;
    }
    __syncthreads();

    // ---- Phase 2: stream 160 x 512 B gathered rows to out ----
    const int g0     = t >> 5;              // 0..7: symbol slot per iteration
    const int lane32 = t & 31;              // float4 slot in the 128-f row

    #pragma unroll 4
    for (int it = 0; it < P2_ITERS; ++it) {
        const int sl  = it * 8 + g0;        // local symbol index
        const float* cb = s_crs[sl] ? cb_c : cb_f;      // L2-resident 256 KB
        const float4 val = ((const float4*)(cb + s_row[sl] * D))[lane32];
        ((float4*)(out + s_off[sl]))[lane32] = val;     // 4 KB contig / iter
    }
}

extern "C" void kernel_launch(void* const* d_in, const int* in_sizes, int n_in,
                              void* d_out, int out_size, void* d_ws, size_t ws_size,
                              hipStream_t stream) {
    const int*   idx_c = (const int*)  d_in[0];
    const int*   idx_f = (const int*)  d_in[1];
    const float* cb_c  = (const float*)d_in[2];
    const float* cb_f  = (const float*)d_in[3];
    const float* u_c   = (const float*)d_in[4];
    const float* u_f   = (const float*)d_in[5];
    float*       out   = (float*)d_out;

    fused_chan_gather<<<GRID, 256, 0, stream>>>(
        idx_c, idx_f, cb_c, cb_f, u_c, u_f, out);
}